// Round 5
// baseline (555.192 us; speedup 1.0000x reference)
//
#include <hip/hip_runtime.h>
#include <math.h>

// LocationAwareAttention: B=16, T=2048, D=1024
// score[b,t] = w_score . tanh( (query@Wq^T + value@Wv^T)[b,t,:] + conv1d(last_attn) + conv_b + bias ) + b_score
// attn = sigmoid(score masked) / rowsum ; context = attn @ value
//
// K1: convert [Wq|Wv] f32 -> Wc fp16 [1024][2048] in ws (4 MB)
// K2: fused GEMM (M=32768,N=1024,K=2048) fp16 MFMA 16x16x32, 128x128x32 tiles,
//     global_load_lds staging (A as f32 + cvt_pkrtz at frag load), XOR-swizzled LDS,
//     epilogue: +conv+bias, tanh, *w_score, 16-lane reduce, atomicAdd -> score
//     (score lives in d_out's attn region, zeroed up front)
// K3: normalize in place: sigmoid + rowsum + divide -> attn
// K4: context GEMV: atomicAdd into d_out[0..16383]

typedef _Float16 f16;
typedef _Float16 f16x4 __attribute__((ext_vector_type(4)));
typedef _Float16 f16x8 __attribute__((ext_vector_type(8)));
typedef __fp16   h16x2 __attribute__((ext_vector_type(2)));   // cvt_pkrtz native type
typedef float f32x4 __attribute__((ext_vector_type(4)));

// ---------------- K1: weight convert ----------------
__global__ void k_convert_w(const float* __restrict__ Wq, const float* __restrict__ Wv,
                            f16* __restrict__ Wc) {
    int idx = (blockIdx.x * 256 + threadIdx.x) * 4;   // element in [0, 1024*2048)
    int e = idx >> 11;
    int k = idx & 2047;
    const float* src = (k < 1024) ? (Wq + e * 1024 + k) : (Wv + e * 1024 + (k - 1024));
    float4 w = *(const float4*)src;
    f16x4 o = { (f16)w.x, (f16)w.y, (f16)w.z, (f16)w.w };
    *(f16x4*)(Wc + idx) = o;
}

// ---------------- K2: fused GEMM + score ----------------
__global__ void __launch_bounds__(256) k_gemm_score(
    const float* __restrict__ query, const float* __restrict__ value,
    const f16* __restrict__ Wc,
    const float* __restrict__ last_attn,
    const float* __restrict__ conv_w, const float* __restrict__ conv_b,
    const float* __restrict__ w_score, const float* __restrict__ bias,
    float* __restrict__ score)
{
    __shared__ __align__(16) char smem[16384 + 8192];   // A f32 [128][32], B f16 [128][32]
    char* As = smem;
    char* Bs = smem + 16384;

    const int tid  = threadIdx.x;
    const int lane = tid & 63;
    const int wid  = tid >> 6;
    const int wm   = wid >> 1, wn = wid & 1;

    // XCD-chunked swizzle: the 8 n-tiles sharing an A-panel run consecutively
    // on ONE XCD (round-robin dispatch: xcd = bid & 7).
    int bid = blockIdx.x;
    int x = bid & 7, s = bid >> 3;
    int m_tile = (x << 5) + (s >> 3);   // [0,256)
    int n_tile = s & 7;                 // [0,8)
    long m0 = (long)m_tile << 7;
    int  n0 = n_tile << 7;

    // ---- staging address precompute (pre-swizzled global source, linear LDS dest) ----
    long aoff[4]; char* adst[4];
#pragma unroll
    for (int i = 0; i < 4; ++i) {
        int idx = i * 256 + tid;                // 16B chunk id of A tile (128 rows x 128B)
        int r  = idx >> 3;
        int cb = (idx & 7) << 4;
        int cbs = cb ^ ((r & 7) << 4);          // XOR swizzle, 16B granular
        aoff[i] = (m0 + r) * 1024 + (cbs >> 2); // f32 elements (k0 added per step)
        adst[i] = As + idx * 16;
    }
    long boff[2]; char* bdst[2];
#pragma unroll
    for (int i = 0; i < 2; ++i) {
        int idx = i * 256 + tid;                // 16B chunk id of B tile (128 rows x 64B)
        int r  = idx >> 2;
        int cb = (idx & 3) << 4;
        int cbs = cb ^ ((r & 3) << 4);
        boff[i] = (long)(n0 + r) * 2048 + (cbs >> 1);   // f16 elements
        bdst[i] = Bs + idx * 16;
    }

    // ---- fragment read byte offsets (same XOR applied on read) ----
    int aRd[4][2], bRd[4];
#pragma unroll
    for (int mi = 0; mi < 4; ++mi) {
        int row = wm * 64 + mi * 16 + (lane & 15);
        int cb0 = (lane >> 4) * 32;             // k-offset in bytes (8 floats/group)
        int sw  = (row & 7) << 4;
        aRd[mi][0] = row * 128 + (cb0 ^ sw);
        aRd[mi][1] = row * 128 + ((cb0 + 16) ^ sw);
    }
#pragma unroll
    for (int ni = 0; ni < 4; ++ni) {
        int e  = wn * 64 + ni * 16 + (lane & 15);
        int cb = (lane >> 4) * 16;              // k-offset in bytes (8 f16/group)
        bRd[ni] = e * 64 + (cb ^ ((e & 3) << 4));
    }

    f32x4 acc[4][4] = {};

    // One K-step: stage tile (A from `src` at f32 element offset k0x, B at f16
    // offset k0g), barrier, read frags, MFMA. Two barriers; m97 structure.
#define K_STEP(src, k0x, k0g)                                                      \
    {                                                                              \
        __syncthreads();                                                           \
        _Pragma("unroll")                                                          \
        for (int i = 0; i < 4; ++i)                                                \
            __builtin_amdgcn_global_load_lds(                                      \
                (const __attribute__((address_space(1))) void*)(src + aoff[i] + (k0x)), \
                (__attribute__((address_space(3))) void*)(adst[i]), 16, 0, 0);     \
        _Pragma("unroll")                                                          \
        for (int i = 0; i < 2; ++i)                                                \
            __builtin_amdgcn_global_load_lds(                                      \
                (const __attribute__((address_space(1))) void*)(Wc + boff[i] + (k0g)), \
                (__attribute__((address_space(3))) void*)(bdst[i]), 16, 0, 0);     \
        __syncthreads();                                                           \
        f16x8 aF[4], bF[4];                                                        \
        _Pragma("unroll")                                                          \
        for (int mi = 0; mi < 4; ++mi) {                                           \
            float4 x0 = *(const float4*)(As + aRd[mi][0]);                         \
            float4 x1 = *(const float4*)(As + aRd[mi][1]);                         \
            union { f16x8 v; h16x2 h[4]; } u;                                      \
            u.h[0] = __builtin_amdgcn_cvt_pkrtz(x0.x, x0.y);                       \
            u.h[1] = __builtin_amdgcn_cvt_pkrtz(x0.z, x0.w);                       \
            u.h[2] = __builtin_amdgcn_cvt_pkrtz(x1.x, x1.y);                       \
            u.h[3] = __builtin_amdgcn_cvt_pkrtz(x1.z, x1.w);                       \
            aF[mi] = u.v;                                                          \
        }                                                                          \
        _Pragma("unroll")                                                          \
        for (int ni = 0; ni < 4; ++ni)                                             \
            bF[ni] = *(const f16x8*)(Bs + bRd[ni]);                                \
        _Pragma("unroll")                                                          \
        for (int mi = 0; mi < 4; ++mi)                                             \
            _Pragma("unroll")                                                      \
            for (int ni = 0; ni < 4; ++ni)                                         \
                acc[mi][ni] = __builtin_amdgcn_mfma_f32_16x16x32_f16(              \
                    aF[mi], bF[ni], acc[mi][ni], 0, 0, 0);                         \
    }

    // kt 0..31: A from query (k 0..1023); kt 32..63: A from value (k 0..1023 of value)
    for (int kt = 0; kt < 32; ++kt)  K_STEP(query, kt * 32, kt * 32);
    for (int kt = 0; kt < 32; ++kt)  K_STEP(value, kt * 32, 1024 + kt * 32);
#undef K_STEP

    // ---- epilogue: conv + bias + tanh + w_score dot, reduce over cols, atomicAdd ----
    float wsc[4], c0[4], c1[4], c2[4], cbb[4];
#pragma unroll
    for (int ni = 0; ni < 4; ++ni) {
        int c = n0 + wn * 64 + ni * 16 + (lane & 15);
        wsc[ni] = w_score[c];
        c0[ni] = conv_w[3 * c];
        c1[ni] = conv_w[3 * c + 1];
        c2[ni] = conv_w[3 * c + 2];
        cbb[ni] = conv_b[c] + bias[c];
    }
    int bb = (int)(m0 >> 11);
    int t0 = (int)(m0 & 2047);
    const float* la = last_attn + bb * 2048;
    float* sc = score + bb * 2048;
#pragma unroll
    for (int mi = 0; mi < 4; ++mi) {
#pragma unroll
        for (int r = 0; r < 4; ++r) {
            int tl = t0 + wm * 64 + mi * 16 + ((lane >> 4) << 2) + r;  // C row (= t within batch)
            float lm = (tl > 0)    ? la[tl - 1] : 0.f;
            float l0 = la[tl];
            float lp = (tl < 2047) ? la[tl + 1] : 0.f;
            float sacc = 0.f;
#pragma unroll
            for (int ni = 0; ni < 4; ++ni) {
                float val = acc[mi][ni][r] + c0[ni] * lm + c1[ni] * l0 + c2[ni] * lp + cbb[ni];
                sacc += wsc[ni] * tanhf(val);
            }
            sacc += __shfl_xor(sacc, 1);
            sacc += __shfl_xor(sacc, 2);
            sacc += __shfl_xor(sacc, 4);
            sacc += __shfl_xor(sacc, 8);
            if ((lane & 15) == 0) atomicAdd(sc + tl, sacc);
        }
    }
}

// ---------------- K3: sigmoid + L1 normalize (in place over score) ----------------
__global__ void k_normalize(float* __restrict__ score, const unsigned char* __restrict__ mask,
                            const float* __restrict__ b_score)
{
    int b = blockIdx.x;
    int tid = threadIdx.x;
    float bs = b_score[0];
    float vals[8];
    float loc = 0.f;
#pragma unroll
    for (int j = 0; j < 8; ++j) {
        int t = j * 256 + tid;
        float xv = score[b * 2048 + t] + bs;
        if (mask[b * 2048 + t]) xv = -1e30f;
        float sg = 1.f / (1.f + expf(-xv));
        vals[j] = sg;
        loc += sg;
    }
#pragma unroll
    for (int off = 1; off < 64; off <<= 1) loc += __shfl_xor(loc, off);
    __shared__ float red[4];
    if ((tid & 63) == 0) red[tid >> 6] = loc;
    __syncthreads();                      // all score reads done before this point
    float inv = 1.f / (red[0] + red[1] + red[2] + red[3]);
#pragma unroll
    for (int j = 0; j < 8; ++j) {
        int t = j * 256 + tid;
        score[b * 2048 + t] = vals[j] * inv;
    }
}

// ---------------- K4: context = attn @ value ----------------
__global__ void k_context(const float* __restrict__ value, const float* __restrict__ attn,
                          float* __restrict__ ctx)
{
    int bidx = blockIdx.x;
    int b  = bidx >> 5;
    int tc = bidx & 31;
    int t0 = tc * 64;
    int tid = threadIdx.x;
    const float4* v4 = (const float4*)(value + (long)(b * 2048 + t0) * 1024) + tid;
    const float* at = attn + b * 2048 + t0;
    float4 a = { 0.f, 0.f, 0.f, 0.f };
    for (int t = 0; t < 64; ++t) {
        float w = at[t];
        float4 v = v4[t * 256];
        a.x += w * v.x; a.y += w * v.y; a.z += w * v.z; a.w += w * v.w;
    }
    float* o = ctx + b * 1024 + tid * 4;
    atomicAdd(o + 0, a.x);
    atomicAdd(o + 1, a.y);
    atomicAdd(o + 2, a.z);
    atomicAdd(o + 3, a.w);
}

extern "C" void kernel_launch(void* const* d_in, const int* in_sizes, int n_in,
                              void* d_out, int out_size, void* d_ws, size_t ws_size,
                              hipStream_t stream)
{
    const float*          query     = (const float*)d_in[0];
    const float*          value     = (const float*)d_in[1];
    const unsigned char*  mask      = (const unsigned char*)d_in[2];
    const float*          last_attn = (const float*)d_in[3];
    const float*          conv_w    = (const float*)d_in[4];
    const float*          conv_b    = (const float*)d_in[5];
    const float*          Wq        = (const float*)d_in[6];
    const float*          Wv        = (const float*)d_in[7];
    const float*          w_score   = (const float*)d_in[8];
    const float*          b_score   = (const float*)d_in[9];
    const float*          bias      = (const float*)d_in[10];

    f16* Wc = (f16*)d_ws;                                   // 4 MB
    if (ws_size < (size_t)4 * 1024 * 1024) return;          // clean incorrect signal

    float* out  = (float*)d_out;
    float* ctx  = out;              // 16*1024  (context, output 0)
    float* attn = out + 16 * 1024;  // 16*2048  (attn, output 1; doubles as score scratch)

    (void)hipMemsetAsync(attn, 0, 16 * 2048 * 4, stream);
    (void)hipMemsetAsync(ctx, 0, 16 * 1024 * 4, stream);
    k_convert_w<<<2048, 256, 0, stream>>>(Wq, Wv, Wc);
    k_gemm_score<<<2048, 256, 0, stream>>>(query, value, Wc, last_attn,
                                           conv_w, conv_b, w_score, bias, attn);
    k_normalize<<<16, 256, 0, stream>>>(attn, mask, b_score);
    k_context<<<512, 256, 0, stream>>>(value, attn, ctx);
}

// Round 6
// 544.419 us; speedup vs baseline: 1.0198x; 1.0198x over previous
//
#include <hip/hip_runtime.h>
#include <math.h>

// LocationAwareAttention: B=16, T=2048, D=1024
// score[b,t] = w_score . tanh( (query@Wq^T + value@Wv^T)[b,t,:] + conv1d(last_attn) + conv_b + bias ) + b_score
// attn = sigmoid(score masked) / rowsum ; context = attn @ value
//
// Fast path (ws >= 132MB):
//   K0: convert query||value -> Xc fp16 [32768][2048], [Wq|Wv] -> Wc fp16 [1024][2048]
//   K2f: m97-structure GEMM, all-fp16 staging (8KB A + 8KB B per step),
//        8 ds_read_b128 + 16 MFMA per wave-step, fused score epilogue.
// Fallback path (small ws): round-5-validated kernel (f32-A staging + cvt_pkrtz).
// K3: sigmoid + L1 normalize in place;  K4: context GEMV.

typedef _Float16 f16;
typedef _Float16 f16x4 __attribute__((ext_vector_type(4)));
typedef _Float16 f16x8 __attribute__((ext_vector_type(8)));
typedef __fp16   h16x2 __attribute__((ext_vector_type(2)));   // cvt_pkrtz native type
typedef float f32x4 __attribute__((ext_vector_type(4)));

// ---------------- K0: unified convert (X and W) ----------------
// grid: 65536 blocks for X (32768x2048 f16) + 2048 blocks for W (1024x2048 f16)
__global__ void k_convert(const float* __restrict__ query, const float* __restrict__ value,
                          const float* __restrict__ Wq, const float* __restrict__ Wv,
                          f16* __restrict__ Xc, f16* __restrict__ Wc)
{
    long g = (long)blockIdx.x * 256 + threadIdx.x;   // float4-group id
    if (blockIdx.x < 65536) {
        long idx = g * 4;                  // element in [0, 32768*2048)
        long m = idx >> 11;                // b*2048 + t
        int  k = (int)(idx & 2047);
        const float* src = (k < 1024) ? (query + m * 1024 + k)
                                      : (value + m * 1024 + (k - 1024));
        float4 w = *(const float4*)src;
        f16x4 o = { (f16)w.x, (f16)w.y, (f16)w.z, (f16)w.w };
        *(f16x4*)(Xc + idx) = o;
    } else {
        long idx = (g - (long)65536 * 256) * 4;      // element in [0, 1024*2048)
        long e = idx >> 11;
        int  k = (int)(idx & 2047);
        const float* src = (k < 1024) ? (Wq + e * 1024 + k)
                                      : (Wv + e * 1024 + (k - 1024));
        float4 w = *(const float4*)src;
        f16x4 o = { (f16)w.x, (f16)w.y, (f16)w.z, (f16)w.w };
        *(f16x4*)(Wc + idx) = o;
    }
}

// ---------------- K2f: fast GEMM + score (all-fp16 staging, m97 structure) ----------------
__global__ void __launch_bounds__(256) k_gemm_f16(
    const f16* __restrict__ Xc, const f16* __restrict__ Wc,
    const float* __restrict__ last_attn,
    const float* __restrict__ conv_w, const float* __restrict__ conv_b,
    const float* __restrict__ w_score, const float* __restrict__ bias,
    float* __restrict__ score)
{
    __shared__ __align__(16) char smem[8192 + 8192];   // A f16 [128][32], B f16 [128][32]
    char* As = smem;
    char* Bs = smem + 8192;

    const int tid  = threadIdx.x;
    const int lane = tid & 63;
    const int wid  = tid >> 6;
    const int wm   = wid >> 1, wn = wid & 1;

    // XCD-chunked swizzle: 8 n-tiles sharing an A-panel run consecutively on one XCD.
    int bid = blockIdx.x;
    int x = bid & 7, s = bid >> 3;
    int m_tile = (x << 5) + (s >> 3);   // [0,256)
    int n_tile = s & 7;                 // [0,8)
    long m0 = (long)m_tile << 7;
    int  n0 = n_tile << 7;

    // ---- staging (pre-swizzled global source, linear LDS dest); 64B rows, XOR (r&3)<<4 ----
    long aoff[2]; char* adst[2];
    long boff[2]; char* bdst[2];
#pragma unroll
    for (int i = 0; i < 2; ++i) {
        int idx = i * 256 + tid;                 // 16B chunk id (128 rows x 4 chunks)
        int r  = idx >> 2;
        int cb = (idx & 3) << 4;
        int cbs = cb ^ ((r & 3) << 4);
        aoff[i] = (m0 + r) * 2048 + (cbs >> 1);  // f16 elements (k0 added per step)
        adst[i] = As + idx * 16;
        boff[i] = (long)(n0 + r) * 2048 + (cbs >> 1);
        bdst[i] = Bs + idx * 16;
    }

    // ---- fragment read byte offsets (same XOR on read) ----
    int aRd[4], bRd[4];
#pragma unroll
    for (int mi = 0; mi < 4; ++mi) {
        int row = wm * 64 + mi * 16 + (lane & 15);
        int cb  = (lane >> 4) * 16;              // k-group byte offset (8 f16)
        aRd[mi] = row * 64 + (cb ^ ((row & 3) << 4));
    }
#pragma unroll
    for (int ni = 0; ni < 4; ++ni) {
        int e  = wn * 64 + ni * 16 + (lane & 15);
        int cb = (lane >> 4) * 16;
        bRd[ni] = e * 64 + (cb ^ ((e & 3) << 4));
    }

    f32x4 acc[4][4] = {};

    for (int kt = 0; kt < 64; ++kt) {
        int k0 = kt * 32;
        __syncthreads();                         // prev-step frag reads done before overwrite
#pragma unroll
        for (int i = 0; i < 2; ++i)
            __builtin_amdgcn_global_load_lds(
                (const __attribute__((address_space(1))) void*)(Xc + aoff[i] + k0),
                (__attribute__((address_space(3))) void*)(adst[i]), 16, 0, 0);
#pragma unroll
        for (int i = 0; i < 2; ++i)
            __builtin_amdgcn_global_load_lds(
                (const __attribute__((address_space(1))) void*)(Wc + boff[i] + k0),
                (__attribute__((address_space(3))) void*)(bdst[i]), 16, 0, 0);
        __syncthreads();                         // compiler drains vmcnt before barrier

        f16x8 aF[4], bF[4];
#pragma unroll
        for (int mi = 0; mi < 4; ++mi) aF[mi] = *(const f16x8*)(As + aRd[mi]);
#pragma unroll
        for (int ni = 0; ni < 4; ++ni) bF[ni] = *(const f16x8*)(Bs + bRd[ni]);
#pragma unroll
        for (int mi = 0; mi < 4; ++mi)
#pragma unroll
            for (int ni = 0; ni < 4; ++ni)
                acc[mi][ni] = __builtin_amdgcn_mfma_f32_16x16x32_f16(
                    aF[mi], bF[ni], acc[mi][ni], 0, 0, 0);
    }

    // ---- epilogue: conv + bias + tanh + w_score dot, 16-lane reduce, atomicAdd ----
    float wsc[4], c0[4], c1[4], c2[4], cbb[4];
#pragma unroll
    for (int ni = 0; ni < 4; ++ni) {
        int c = n0 + wn * 64 + ni * 16 + (lane & 15);
        wsc[ni] = w_score[c];
        c0[ni] = conv_w[3 * c];
        c1[ni] = conv_w[3 * c + 1];
        c2[ni] = conv_w[3 * c + 2];
        cbb[ni] = conv_b[c] + bias[c];
    }
    int bb = (int)(m0 >> 11);
    int t0 = (int)(m0 & 2047);
    const float* la = last_attn + bb * 2048;
    float* sc = score + bb * 2048;
#pragma unroll
    for (int mi = 0; mi < 4; ++mi) {
#pragma unroll
        for (int r = 0; r < 4; ++r) {
            int tl = t0 + wm * 64 + mi * 16 + ((lane >> 4) << 2) + r;
            float lm = (tl > 0)    ? la[tl - 1] : 0.f;
            float l0 = la[tl];
            float lp = (tl < 2047) ? la[tl + 1] : 0.f;
            float sacc = 0.f;
#pragma unroll
            for (int ni = 0; ni < 4; ++ni) {
                float val = acc[mi][ni][r] + c0[ni] * lm + c1[ni] * l0 + c2[ni] * lp + cbb[ni];
                sacc += wsc[ni] * tanhf(val);
            }
            sacc += __shfl_xor(sacc, 1);
            sacc += __shfl_xor(sacc, 2);
            sacc += __shfl_xor(sacc, 4);
            sacc += __shfl_xor(sacc, 8);
            if ((lane & 15) == 0) atomicAdd(sc + tl, sacc);
        }
    }
}

// ---------------- Fallback path (round-5-validated): K1 + K2 ----------------
__global__ void k_convert_w(const float* __restrict__ Wq, const float* __restrict__ Wv,
                            f16* __restrict__ Wc) {
    int idx = (blockIdx.x * 256 + threadIdx.x) * 4;
    int e = idx >> 11;
    int k = idx & 2047;
    const float* src = (k < 1024) ? (Wq + e * 1024 + k) : (Wv + e * 1024 + (k - 1024));
    float4 w = *(const float4*)src;
    f16x4 o = { (f16)w.x, (f16)w.y, (f16)w.z, (f16)w.w };
    *(f16x4*)(Wc + idx) = o;
}

__global__ void __launch_bounds__(256) k_gemm_score(
    const float* __restrict__ query, const float* __restrict__ value,
    const f16* __restrict__ Wc,
    const float* __restrict__ last_attn,
    const float* __restrict__ conv_w, const float* __restrict__ conv_b,
    const float* __restrict__ w_score, const float* __restrict__ bias,
    float* __restrict__ score)
{
    __shared__ __align__(16) char smem[16384 + 8192];
    char* As = smem;
    char* Bs = smem + 16384;

    const int tid  = threadIdx.x;
    const int lane = tid & 63;
    const int wid  = tid >> 6;
    const int wm   = wid >> 1, wn = wid & 1;

    int bid = blockIdx.x;
    int x = bid & 7, s = bid >> 3;
    int m_tile = (x << 5) + (s >> 3);
    int n_tile = s & 7;
    long m0 = (long)m_tile << 7;
    int  n0 = n_tile << 7;

    long aoff[4]; char* adst[4];
#pragma unroll
    for (int i = 0; i < 4; ++i) {
        int idx = i * 256 + tid;
        int r  = idx >> 3;
        int cb = (idx & 7) << 4;
        int cbs = cb ^ ((r & 7) << 4);
        aoff[i] = (m0 + r) * 1024 + (cbs >> 2);
        adst[i] = As + idx * 16;
    }
    long boff[2]; char* bdst[2];
#pragma unroll
    for (int i = 0; i < 2; ++i) {
        int idx = i * 256 + tid;
        int r  = idx >> 2;
        int cb = (idx & 3) << 4;
        int cbs = cb ^ ((r & 3) << 4);
        boff[i] = (long)(n0 + r) * 2048 + (cbs >> 1);
        bdst[i] = Bs + idx * 16;
    }

    int aRd[4][2], bRd[4];
#pragma unroll
    for (int mi = 0; mi < 4; ++mi) {
        int row = wm * 64 + mi * 16 + (lane & 15);
        int cb0 = (lane >> 4) * 32;
        int sw  = (row & 7) << 4;
        aRd[mi][0] = row * 128 + (cb0 ^ sw);
        aRd[mi][1] = row * 128 + ((cb0 + 16) ^ sw);
    }
#pragma unroll
    for (int ni = 0; ni < 4; ++ni) {
        int e  = wn * 64 + ni * 16 + (lane & 15);
        int cb = (lane >> 4) * 16;
        bRd[ni] = e * 64 + (cb ^ ((e & 3) << 4));
    }

    f32x4 acc[4][4] = {};

#define K_STEP(src, k0x, k0g)                                                      \
    {                                                                              \
        __syncthreads();                                                           \
        _Pragma("unroll")                                                          \
        for (int i = 0; i < 4; ++i)                                                \
            __builtin_amdgcn_global_load_lds(                                      \
                (const __attribute__((address_space(1))) void*)(src + aoff[i] + (k0x)), \
                (__attribute__((address_space(3))) void*)(adst[i]), 16, 0, 0);     \
        _Pragma("unroll")                                                          \
        for (int i = 0; i < 2; ++i)                                                \
            __builtin_amdgcn_global_load_lds(                                      \
                (const __attribute__((address_space(1))) void*)(Wc + boff[i] + (k0g)), \
                (__attribute__((address_space(3))) void*)(bdst[i]), 16, 0, 0);     \
        __syncthreads();                                                           \
        f16x8 aF[4], bF[4];                                                        \
        _Pragma("unroll")                                                          \
        for (int mi = 0; mi < 4; ++mi) {                                           \
            float4 x0 = *(const float4*)(As + aRd[mi][0]);                         \
            float4 x1 = *(const float4*)(As + aRd[mi][1]);                         \
            union { f16x8 v; h16x2 h[4]; } u;                                      \
            u.h[0] = __builtin_amdgcn_cvt_pkrtz(x0.x, x0.y);                       \
            u.h[1] = __builtin_amdgcn_cvt_pkrtz(x0.z, x0.w);                       \
            u.h[2] = __builtin_amdgcn_cvt_pkrtz(x1.x, x1.y);                       \
            u.h[3] = __builtin_amdgcn_cvt_pkrtz(x1.z, x1.w);                       \
            aF[mi] = u.v;                                                          \
        }                                                                          \
        _Pragma("unroll")                                                          \
        for (int ni = 0; ni < 4; ++ni)                                             \
            bF[ni] = *(const f16x8*)(Bs + bRd[ni]);                                \
        _Pragma("unroll")                                                          \
        for (int mi = 0; mi < 4; ++mi)                                             \
            _Pragma("unroll")                                                      \
            for (int ni = 0; ni < 4; ++ni)                                         \
                acc[mi][ni] = __builtin_amdgcn_mfma_f32_16x16x32_f16(              \
                    aF[mi], bF[ni], acc[mi][ni], 0, 0, 0);                         \
    }

    for (int kt = 0; kt < 32; ++kt)  K_STEP(query, kt * 32, kt * 32);
    for (int kt = 0; kt < 32; ++kt)  K_STEP(value, kt * 32, 1024 + kt * 32);
#undef K_STEP

    float wsc[4], c0[4], c1[4], c2[4], cbb[4];
#pragma unroll
    for (int ni = 0; ni < 4; ++ni) {
        int c = n0 + wn * 64 + ni * 16 + (lane & 15);
        wsc[ni] = w_score[c];
        c0[ni] = conv_w[3 * c];
        c1[ni] = conv_w[3 * c + 1];
        c2[ni] = conv_w[3 * c + 2];
        cbb[ni] = conv_b[c] + bias[c];
    }
    int bb = (int)(m0 >> 11);
    int t0 = (int)(m0 & 2047);
    const float* la = last_attn + bb * 2048;
    float* sc = score + bb * 2048;
#pragma unroll
    for (int mi = 0; mi < 4; ++mi) {
#pragma unroll
        for (int r = 0; r < 4; ++r) {
            int tl = t0 + wm * 64 + mi * 16 + ((lane >> 4) << 2) + r;
            float lm = (tl > 0)    ? la[tl - 1] : 0.f;
            float l0 = la[tl];
            float lp = (tl < 2047) ? la[tl + 1] : 0.f;
            float sacc = 0.f;
#pragma unroll
            for (int ni = 0; ni < 4; ++ni) {
                float val = acc[mi][ni][r] + c0[ni] * lm + c1[ni] * l0 + c2[ni] * lp + cbb[ni];
                sacc += wsc[ni] * tanhf(val);
            }
            sacc += __shfl_xor(sacc, 1);
            sacc += __shfl_xor(sacc, 2);
            sacc += __shfl_xor(sacc, 4);
            sacc += __shfl_xor(sacc, 8);
            if ((lane & 15) == 0) atomicAdd(sc + tl, sacc);
        }
    }
}

// ---------------- K3: sigmoid + L1 normalize (in place over score) ----------------
__global__ void k_normalize(float* __restrict__ score, const unsigned char* __restrict__ mask,
                            const float* __restrict__ b_score)
{
    int b = blockIdx.x;
    int tid = threadIdx.x;
    float bs = b_score[0];
    float vals[8];
    float loc = 0.f;
#pragma unroll
    for (int j = 0; j < 8; ++j) {
        int t = j * 256 + tid;
        float xv = score[b * 2048 + t] + bs;
        if (mask[b * 2048 + t]) xv = -1e30f;
        float sg = 1.f / (1.f + expf(-xv));
        vals[j] = sg;
        loc += sg;
    }
#pragma unroll
    for (int off = 1; off < 64; off <<= 1) loc += __shfl_xor(loc, off);
    __shared__ float red[4];
    if ((tid & 63) == 0) red[tid >> 6] = loc;
    __syncthreads();
    float inv = 1.f / (red[0] + red[1] + red[2] + red[3]);
#pragma unroll
    for (int j = 0; j < 8; ++j) {
        int t = j * 256 + tid;
        score[b * 2048 + t] = vals[j] * inv;
    }
}

// ---------------- K4: context = attn @ value ----------------
__global__ void k_context(const float* __restrict__ value, const float* __restrict__ attn,
                          float* __restrict__ ctx)
{
    int bidx = blockIdx.x;
    int b  = bidx >> 5;
    int tc = bidx & 31;
    int t0 = tc * 64;
    int tid = threadIdx.x;
    const float4* v4 = (const float4*)(value + (long)(b * 2048 + t0) * 1024) + tid;
    const float* at = attn + b * 2048 + t0;
    float4 a = { 0.f, 0.f, 0.f, 0.f };
    for (int t = 0; t < 64; ++t) {
        float w = at[t];
        float4 v = v4[t * 256];
        a.x += w * v.x; a.y += w * v.y; a.z += w * v.z; a.w += w * v.w;
    }
    float* o = ctx + b * 1024 + tid * 4;
    atomicAdd(o + 0, a.x);
    atomicAdd(o + 1, a.y);
    atomicAdd(o + 2, a.z);
    atomicAdd(o + 3, a.w);
}

extern "C" void kernel_launch(void* const* d_in, const int* in_sizes, int n_in,
                              void* d_out, int out_size, void* d_ws, size_t ws_size,
                              hipStream_t stream)
{
    const float*          query     = (const float*)d_in[0];
    const float*          value     = (const float*)d_in[1];
    const unsigned char*  mask      = (const unsigned char*)d_in[2];
    const float*          last_attn = (const float*)d_in[3];
    const float*          conv_w    = (const float*)d_in[4];
    const float*          conv_b    = (const float*)d_in[5];
    const float*          Wq        = (const float*)d_in[6];
    const float*          Wv        = (const float*)d_in[7];
    const float*          w_score   = (const float*)d_in[8];
    const float*          b_score   = (const float*)d_in[9];
    const float*          bias      = (const float*)d_in[10];

    float* out  = (float*)d_out;
    float* ctx  = out;              // 16*1024  (context, output 0)
    float* attn = out + 16 * 1024;  // 16*2048  (attn, output 1; doubles as score scratch)

    (void)hipMemsetAsync(attn, 0, 16 * 2048 * 4, stream);
    (void)hipMemsetAsync(ctx, 0, 16 * 1024 * 4, stream);

    const size_t xbytes = (size_t)32768 * 2048 * 2;   // 128 MB
    const size_t wbytes = (size_t)1024 * 2048 * 2;    //   4 MB

    if (ws_size >= xbytes + wbytes) {
        // Fast path: all-fp16 GEMM with pre-converted X.
        f16* Xc = (f16*)d_ws;
        f16* Wc = (f16*)((char*)d_ws + xbytes);
        k_convert<<<65536 + 2048, 256, 0, stream>>>(query, value, Wq, Wv, Xc, Wc);
        k_gemm_f16<<<2048, 256, 0, stream>>>(Xc, Wc, last_attn,
                                             conv_w, conv_b, w_score, bias, attn);
    } else if (ws_size >= wbytes) {
        // Fallback: round-5-validated path (f32 A staging + cvt in-loop).
        f16* Wc = (f16*)d_ws;
        k_convert_w<<<2048, 256, 0, stream>>>(Wq, Wv, Wc);
        k_gemm_score<<<2048, 256, 0, stream>>>(query, value, Wc, last_attn,
                                               conv_w, conv_b, w_score, bias, attn);
    } else {
        return;  // clean incorrect signal rather than corruption
    }

    k_normalize<<<16, 256, 0, stream>>>(attn, mask, b_score);
    k_context<<<512, 256, 0, stream>>>(value, attn, ctx);
}

// Round 7
// 533.099 us; speedup vs baseline: 1.0414x; 1.0212x over previous
//
#include <hip/hip_runtime.h>
#include <math.h>

// LocationAwareAttention: B=16, T=2048, D=1024
// score[b,t] = w_score . tanh( (query@Wq^T + value@Wv^T)[b,t,:] + conv1d(last_attn) + conv_b + bias ) + b_score
// attn = sigmoid(score masked) / rowsum ; context = attn @ value
//
// Fast path (ws >= 132MB):
//   K0: convert query||value -> Xc fp16 [32768][2048], [Wq|Wv] -> Wc fp16 [1024][2048]
//   K2f: m97-structure GEMM + 2-phase double-buffered staging (T3 minimum recipe):
//        STAGE(t+1) issued BEFORE compute(t); ONE __syncthreads per K-step.
//        LDS 32KB = A0|B0|A1|B1 (8KB each). Fused score epilogue.
// Fallback path (small ws): round-5-validated kernel (f32-A staging + cvt_pkrtz).
// K3: sigmoid + L1 normalize in place;  K4: context GEMV.

typedef _Float16 f16;
typedef _Float16 f16x4 __attribute__((ext_vector_type(4)));
typedef _Float16 f16x8 __attribute__((ext_vector_type(8)));
typedef __fp16   h16x2 __attribute__((ext_vector_type(2)));   // cvt_pkrtz native type
typedef float f32x4 __attribute__((ext_vector_type(4)));

// ---------------- K0: unified convert (X and W) ----------------
__global__ void k_convert(const float* __restrict__ query, const float* __restrict__ value,
                          const float* __restrict__ Wq, const float* __restrict__ Wv,
                          f16* __restrict__ Xc, f16* __restrict__ Wc)
{
    long g = (long)blockIdx.x * 256 + threadIdx.x;   // float4-group id
    if (blockIdx.x < 65536) {
        long idx = g * 4;                  // element in [0, 32768*2048)
        long m = idx >> 11;                // b*2048 + t
        int  k = (int)(idx & 2047);
        const float* src = (k < 1024) ? (query + m * 1024 + k)
                                      : (value + m * 1024 + (k - 1024));
        float4 w = *(const float4*)src;
        f16x4 o = { (f16)w.x, (f16)w.y, (f16)w.z, (f16)w.w };
        *(f16x4*)(Xc + idx) = o;
    } else {
        long idx = (g - (long)65536 * 256) * 4;      // element in [0, 1024*2048)
        long e = idx >> 11;
        int  k = (int)(idx & 2047);
        const float* src = (k < 1024) ? (Wq + e * 1024 + k)
                                      : (Wv + e * 1024 + (k - 1024));
        float4 w = *(const float4*)src;
        f16x4 o = { (f16)w.x, (f16)w.y, (f16)w.z, (f16)w.w };
        *(f16x4*)(Wc + idx) = o;
    }
}

// ---------------- K2f: fast GEMM + score (fp16, 2-phase dbuf) ----------------
__global__ void __launch_bounds__(256) k_gemm_f16(
    const f16* __restrict__ Xc, const f16* __restrict__ Wc,
    const float* __restrict__ last_attn,
    const float* __restrict__ conv_w, const float* __restrict__ conv_b,
    const float* __restrict__ w_score, const float* __restrict__ bias,
    float* __restrict__ score)
{
    // Layout: [A0 8K][B0 8K][A1 8K][B1 8K] ; half h base = h*16384.
    __shared__ __align__(16) char smem[4 * 8192];

    const int tid  = threadIdx.x;
    const int lane = tid & 63;
    const int wid  = tid >> 6;
    const int wm   = wid >> 1, wn = wid & 1;

    // XCD-chunked swizzle: 8 n-tiles sharing an A-panel run consecutively on one XCD.
    int bid = blockIdx.x;
    int x = bid & 7, s = bid >> 3;
    int m_tile = (x << 5) + (s >> 3);   // [0,256)
    int n_tile = s & 7;                 // [0,8)
    long m0 = (long)m_tile << 7;
    int  n0 = n_tile << 7;

    // ---- staging (pre-swizzled global source, linear LDS dest); 64B rows, XOR (r&3)<<4 ----
    long aoff[2]; char* adst0[2];
    long boff[2]; char* bdst0[2];
#pragma unroll
    for (int i = 0; i < 2; ++i) {
        int idx = i * 256 + tid;                 // 16B chunk id (128 rows x 4 chunks)
        int r  = idx >> 2;
        int cb = (idx & 3) << 4;
        int cbs = cb ^ ((r & 3) << 4);
        aoff[i] = (m0 + r) * 2048 + (cbs >> 1);  // f16 elements (k0 added per step)
        adst0[i] = smem + idx * 16;              // A half-0 base
        boff[i] = (long)(n0 + r) * 2048 + (cbs >> 1);
        bdst0[i] = smem + 8192 + idx * 16;       // B half-0 base
    }

    // ---- fragment read byte offsets (same XOR on read), relative to half base ----
    int aRd[4], bRd[4];
#pragma unroll
    for (int mi = 0; mi < 4; ++mi) {
        int row = wm * 64 + mi * 16 + (lane & 15);
        int cb  = (lane >> 4) * 16;              // k-group byte offset (8 f16)
        aRd[mi] = row * 64 + (cb ^ ((row & 3) << 4));
    }
#pragma unroll
    for (int ni = 0; ni < 4; ++ni) {
        int e  = wn * 64 + ni * 16 + (lane & 15);
        int cb = (lane >> 4) * 16;
        bRd[ni] = e * 64 + (cb ^ ((e & 3) << 4)) + 8192;
    }

    f32x4 acc[4][4] = {};

#define STAGE(half, k0)                                                            \
    {                                                                              \
        _Pragma("unroll")                                                          \
        for (int i = 0; i < 2; ++i)                                                \
            __builtin_amdgcn_global_load_lds(                                      \
                (const __attribute__((address_space(1))) void*)(Xc + aoff[i] + (k0)), \
                (__attribute__((address_space(3))) void*)(adst0[i] + (half) * 16384), 16, 0, 0); \
        _Pragma("unroll")                                                          \
        for (int i = 0; i < 2; ++i)                                                \
            __builtin_amdgcn_global_load_lds(                                      \
                (const __attribute__((address_space(1))) void*)(Wc + boff[i] + (k0)), \
                (__attribute__((address_space(3))) void*)(bdst0[i] + (half) * 16384), 16, 0, 0); \
    }

#define COMPUTE(half)                                                              \
    {                                                                              \
        const char* base = smem + (half) * 16384;                                  \
        f16x8 aF[4], bF[4];                                                        \
        _Pragma("unroll")                                                          \
        for (int mi = 0; mi < 4; ++mi) aF[mi] = *(const f16x8*)(base + aRd[mi]);   \
        _Pragma("unroll")                                                          \
        for (int ni = 0; ni < 4; ++ni) bF[ni] = *(const f16x8*)(base + bRd[ni]);   \
        _Pragma("unroll")                                                          \
        for (int mi = 0; mi < 4; ++mi)                                             \
            _Pragma("unroll")                                                      \
            for (int ni = 0; ni < 4; ++ni)                                         \
                acc[mi][ni] = __builtin_amdgcn_mfma_f32_16x16x32_f16(              \
                    aF[mi], bF[ni], acc[mi][ni], 0, 0, 0);                         \
    }

    // Prologue: stage tile 0 into half 0; barrier drains vmcnt -> buf0 ready.
    STAGE(0, 0);
    __syncthreads();
    int cur = 0;
    // Main loop: issue next-tile loads, compute current, single barrier.
    // Barrier guarantees: (a) this tile's reads done before next STAGE overwrites,
    // (b) next tile's loads drained (compiler's vmcnt(0) before s_barrier).
    for (int kt = 0; kt < 63; ++kt) {
        STAGE(cur ^ 1, (kt + 1) * 32);
        COMPUTE(cur);
        __syncthreads();
        cur ^= 1;
    }
    COMPUTE(cur);    // last tile; epilogue reads only registers/globals
#undef STAGE
#undef COMPUTE

    // ---- epilogue: conv + bias + tanh + w_score dot, 16-lane reduce, atomicAdd ----
    float wsc[4], c0[4], c1[4], c2[4], cbb[4];
#pragma unroll
    for (int ni = 0; ni < 4; ++ni) {
        int c = n0 + wn * 64 + ni * 16 + (lane & 15);
        wsc[ni] = w_score[c];
        c0[ni] = conv_w[3 * c];
        c1[ni] = conv_w[3 * c + 1];
        c2[ni] = conv_w[3 * c + 2];
        cbb[ni] = conv_b[c] + bias[c];
    }
    int bb = (int)(m0 >> 11);
    int t0 = (int)(m0 & 2047);
    const float* la = last_attn + bb * 2048;
    float* sc = score + bb * 2048;
#pragma unroll
    for (int mi = 0; mi < 4; ++mi) {
#pragma unroll
        for (int r = 0; r < 4; ++r) {
            int tl = t0 + wm * 64 + mi * 16 + ((lane >> 4) << 2) + r;
            float lm = (tl > 0)    ? la[tl - 1] : 0.f;
            float l0 = la[tl];
            float lp = (tl < 2047) ? la[tl + 1] : 0.f;
            float sacc = 0.f;
#pragma unroll
            for (int ni = 0; ni < 4; ++ni) {
                float val = acc[mi][ni][r] + c0[ni] * lm + c1[ni] * l0 + c2[ni] * lp + cbb[ni];
                sacc += wsc[ni] * tanhf(val);
            }
            sacc += __shfl_xor(sacc, 1);
            sacc += __shfl_xor(sacc, 2);
            sacc += __shfl_xor(sacc, 4);
            sacc += __shfl_xor(sacc, 8);
            if ((lane & 15) == 0) atomicAdd(sc + tl, sacc);
        }
    }
}

// ---------------- Fallback path (round-5-validated): K1 + K2 ----------------
__global__ void k_convert_w(const float* __restrict__ Wq, const float* __restrict__ Wv,
                            f16* __restrict__ Wc) {
    int idx = (blockIdx.x * 256 + threadIdx.x) * 4;
    int e = idx >> 11;
    int k = idx & 2047;
    const float* src = (k < 1024) ? (Wq + e * 1024 + k) : (Wv + e * 1024 + (k - 1024));
    float4 w = *(const float4*)src;
    f16x4 o = { (f16)w.x, (f16)w.y, (f16)w.z, (f16)w.w };
    *(f16x4*)(Wc + idx) = o;
}

__global__ void __launch_bounds__(256) k_gemm_score(
    const float* __restrict__ query, const float* __restrict__ value,
    const f16* __restrict__ Wc,
    const float* __restrict__ last_attn,
    const float* __restrict__ conv_w, const float* __restrict__ conv_b,
    const float* __restrict__ w_score, const float* __restrict__ bias,
    float* __restrict__ score)
{
    __shared__ __align__(16) char smem[16384 + 8192];
    char* As = smem;
    char* Bs = smem + 16384;

    const int tid  = threadIdx.x;
    const int lane = tid & 63;
    const int wid  = tid >> 6;
    const int wm   = wid >> 1, wn = wid & 1;

    int bid = blockIdx.x;
    int x = bid & 7, s = bid >> 3;
    int m_tile = (x << 5) + (s >> 3);
    int n_tile = s & 7;
    long m0 = (long)m_tile << 7;
    int  n0 = n_tile << 7;

    long aoff[4]; char* adst[4];
#pragma unroll
    for (int i = 0; i < 4; ++i) {
        int idx = i * 256 + tid;
        int r  = idx >> 3;
        int cb = (idx & 7) << 4;
        int cbs = cb ^ ((r & 7) << 4);
        aoff[i] = (m0 + r) * 1024 + (cbs >> 2);
        adst[i] = As + idx * 16;
    }
    long boff[2]; char* bdst[2];
#pragma unroll
    for (int i = 0; i < 2; ++i) {
        int idx = i * 256 + tid;
        int r  = idx >> 2;
        int cb = (idx & 3) << 4;
        int cbs = cb ^ ((r & 3) << 4);
        boff[i] = (long)(n0 + r) * 2048 + (cbs >> 1);
        bdst[i] = Bs + idx * 16;
    }

    int aRd[4][2], bRd[4];
#pragma unroll
    for (int mi = 0; mi < 4; ++mi) {
        int row = wm * 64 + mi * 16 + (lane & 15);
        int cb0 = (lane >> 4) * 32;
        int sw  = (row & 7) << 4;
        aRd[mi][0] = row * 128 + (cb0 ^ sw);
        aRd[mi][1] = row * 128 + ((cb0 + 16) ^ sw);
    }
#pragma unroll
    for (int ni = 0; ni < 4; ++ni) {
        int e  = wn * 64 + ni * 16 + (lane & 15);
        int cb = (lane >> 4) * 16;
        bRd[ni] = e * 64 + (cb ^ ((e & 3) << 4));
    }

    f32x4 acc[4][4] = {};

#define K_STEP(src, k0x, k0g)                                                      \
    {                                                                              \
        __syncthreads();                                                           \
        _Pragma("unroll")                                                          \
        for (int i = 0; i < 4; ++i)                                                \
            __builtin_amdgcn_global_load_lds(                                      \
                (const __attribute__((address_space(1))) void*)(src + aoff[i] + (k0x)), \
                (__attribute__((address_space(3))) void*)(adst[i]), 16, 0, 0);     \
        _Pragma("unroll")                                                          \
        for (int i = 0; i < 2; ++i)                                                \
            __builtin_amdgcn_global_load_lds(                                      \
                (const __attribute__((address_space(1))) void*)(Wc + boff[i] + (k0g)), \
                (__attribute__((address_space(3))) void*)(bdst[i]), 16, 0, 0);     \
        __syncthreads();                                                           \
        f16x8 aF[4], bF[4];                                                        \
        _Pragma("unroll")                                                          \
        for (int mi = 0; mi < 4; ++mi) {                                           \
            float4 x0 = *(const float4*)(As + aRd[mi][0]);                         \
            float4 x1 = *(const float4*)(As + aRd[mi][1]);                         \
            union { f16x8 v; h16x2 h[4]; } u;                                      \
            u.h[0] = __builtin_amdgcn_cvt_pkrtz(x0.x, x0.y);                       \
            u.h[1] = __builtin_amdgcn_cvt_pkrtz(x0.z, x0.w);                       \
            u.h[2] = __builtin_amdgcn_cvt_pkrtz(x1.x, x1.y);                       \
            u.h[3] = __builtin_amdgcn_cvt_pkrtz(x1.z, x1.w);                       \
            aF[mi] = u.v;                                                          \
        }                                                                          \
        _Pragma("unroll")                                                          \
        for (int ni = 0; ni < 4; ++ni)                                             \
            bF[ni] = *(const f16x8*)(Bs + bRd[ni]);                                \
        _Pragma("unroll")                                                          \
        for (int mi = 0; mi < 4; ++mi)                                             \
            _Pragma("unroll")                                                      \
            for (int ni = 0; ni < 4; ++ni)                                         \
                acc[mi][ni] = __builtin_amdgcn_mfma_f32_16x16x32_f16(              \
                    aF[mi], bF[ni], acc[mi][ni], 0, 0, 0);                         \
    }

    for (int kt = 0; kt < 32; ++kt)  K_STEP(query, kt * 32, kt * 32);
    for (int kt = 0; kt < 32; ++kt)  K_STEP(value, kt * 32, 1024 + kt * 32);
#undef K_STEP

    float wsc[4], c0[4], c1[4], c2[4], cbb[4];
#pragma unroll
    for (int ni = 0; ni < 4; ++ni) {
        int c = n0 + wn * 64 + ni * 16 + (lane & 15);
        wsc[ni] = w_score[c];
        c0[ni] = conv_w[3 * c];
        c1[ni] = conv_w[3 * c + 1];
        c2[ni] = conv_w[3 * c + 2];
        cbb[ni] = conv_b[c] + bias[c];
    }
    int bb = (int)(m0 >> 11);
    int t0 = (int)(m0 & 2047);
    const float* la = last_attn + bb * 2048;
    float* sc = score + bb * 2048;
#pragma unroll
    for (int mi = 0; mi < 4; ++mi) {
#pragma unroll
        for (int r = 0; r < 4; ++r) {
            int tl = t0 + wm * 64 + mi * 16 + ((lane >> 4) << 2) + r;
            float lm = (tl > 0)    ? la[tl - 1] : 0.f;
            float l0 = la[tl];
            float lp = (tl < 2047) ? la[tl + 1] : 0.f;
            float sacc = 0.f;
#pragma unroll
            for (int ni = 0; ni < 4; ++ni) {
                float val = acc[mi][ni][r] + c0[ni] * lm + c1[ni] * l0 + c2[ni] * lp + cbb[ni];
                sacc += wsc[ni] * tanhf(val);
            }
            sacc += __shfl_xor(sacc, 1);
            sacc += __shfl_xor(sacc, 2);
            sacc += __shfl_xor(sacc, 4);
            sacc += __shfl_xor(sacc, 8);
            if ((lane & 15) == 0) atomicAdd(sc + tl, sacc);
        }
    }
}

// ---------------- K3: sigmoid + L1 normalize (in place over score) ----------------
__global__ void k_normalize(float* __restrict__ score, const unsigned char* __restrict__ mask,
                            const float* __restrict__ b_score)
{
    int b = blockIdx.x;
    int tid = threadIdx.x;
    float bs = b_score[0];
    float vals[8];
    float loc = 0.f;
#pragma unroll
    for (int j = 0; j < 8; ++j) {
        int t = j * 256 + tid;
        float xv = score[b * 2048 + t] + bs;
        if (mask[b * 2048 + t]) xv = -1e30f;
        float sg = 1.f / (1.f + expf(-xv));
        vals[j] = sg;
        loc += sg;
    }
#pragma unroll
    for (int off = 1; off < 64; off <<= 1) loc += __shfl_xor(loc, off);
    __shared__ float red[4];
    if ((tid & 63) == 0) red[tid >> 6] = loc;
    __syncthreads();
    float inv = 1.f / (red[0] + red[1] + red[2] + red[3]);
#pragma unroll
    for (int j = 0; j < 8; ++j) {
        int t = j * 256 + tid;
        score[b * 2048 + t] = vals[j] * inv;
    }
}

// ---------------- K4: context = attn @ value ----------------
__global__ void k_context(const float* __restrict__ value, const float* __restrict__ attn,
                          float* __restrict__ ctx)
{
    int bidx = blockIdx.x;
    int b  = bidx >> 5;
    int tc = bidx & 31;
    int t0 = tc * 64;
    int tid = threadIdx.x;
    const float4* v4 = (const float4*)(value + (long)(b * 2048 + t0) * 1024) + tid;
    const float* at = attn + b * 2048 + t0;
    float4 a = { 0.f, 0.f, 0.f, 0.f };
    for (int t = 0; t < 64; ++t) {
        float w = at[t];
        float4 v = v4[t * 256];
        a.x += w * v.x; a.y += w * v.y; a.z += w * v.z; a.w += w * v.w;
    }
    float* o = ctx + b * 1024 + tid * 4;
    atomicAdd(o + 0, a.x);
    atomicAdd(o + 1, a.y);
    atomicAdd(o + 2, a.z);
    atomicAdd(o + 3, a.w);
}

extern "C" void kernel_launch(void* const* d_in, const int* in_sizes, int n_in,
                              void* d_out, int out_size, void* d_ws, size_t ws_size,
                              hipStream_t stream)
{
    const float*          query     = (const float*)d_in[0];
    const float*          value     = (const float*)d_in[1];
    const unsigned char*  mask      = (const unsigned char*)d_in[2];
    const float*          last_attn = (const float*)d_in[3];
    const float*          conv_w    = (const float*)d_in[4];
    const float*          conv_b    = (const float*)d_in[5];
    const float*          Wq        = (const float*)d_in[6];
    const float*          Wv        = (const float*)d_in[7];
    const float*          w_score   = (const float*)d_in[8];
    const float*          b_score   = (const float*)d_in[9];
    const float*          bias      = (const float*)d_in[10];

    float* out  = (float*)d_out;
    float* ctx  = out;              // 16*1024  (context, output 0)
    float* attn = out + 16 * 1024;  // 16*2048  (attn, output 1; doubles as score scratch)

    (void)hipMemsetAsync(attn, 0, 16 * 2048 * 4, stream);
    (void)hipMemsetAsync(ctx, 0, 16 * 1024 * 4, stream);

    const size_t xbytes = (size_t)32768 * 2048 * 2;   // 128 MB
    const size_t wbytes = (size_t)1024 * 2048 * 2;    //   4 MB

    if (ws_size >= xbytes + wbytes) {
        // Fast path: all-fp16 GEMM with pre-converted X, 2-phase dbuf pipeline.
        f16* Xc = (f16*)d_ws;
        f16* Wc = (f16*)((char*)d_ws + xbytes);
        k_convert<<<65536 + 2048, 256, 0, stream>>>(query, value, Wq, Wv, Xc, Wc);
        k_gemm_f16<<<2048, 256, 0, stream>>>(Xc, Wc, last_attn,
                                             conv_w, conv_b, w_score, bias, attn);
    } else if (ws_size >= wbytes) {
        // Fallback: round-5-validated path (f32 A staging + cvt in-loop).
        f16* Wc = (f16*)d_ws;
        k_convert_w<<<2048, 256, 0, stream>>>(Wq, Wv, Wc);
        k_gemm_score<<<2048, 256, 0, stream>>>(query, value, Wc, last_attn,
                                               conv_w, conv_b, w_score, bias, attn);
    } else {
        return;  // clean incorrect signal rather than corruption
    }

    k_normalize<<<16, 256, 0, stream>>>(attn, mask, b_score);
    k_context<<<512, 256, 0, stream>>>(value, attn, ctx);
}